// Round 6
// baseline (926.081 us; speedup 1.0000x reference)
//
#include <hip/hip_runtime.h>
#include <math.h>

typedef unsigned int uint;

__device__ inline uint packbf2(float a, float b) {
  uint ua = __float_as_uint(a), ub = __float_as_uint(b);
  ua = (ua + 0x7fffu + ((ua >> 16) & 1u)) >> 16;
  ub = (ub + 0x7fffu + ((ub >> 16) & 1u)) & 0xffff0000u;
  return ua | ub;
}
__device__ inline float bflo(uint u) { return __uint_as_float(u << 16); }
__device__ inline float bfhi(uint u) { return __uint_as_float(u & 0xffff0000u); }

// ---------------- CSR build ----------------
__global__ void hist_k(const int* __restrict__ dst, int* __restrict__ cnt, int E) {
  int stride = gridDim.x * blockDim.x;
  for (int e = blockIdx.x * blockDim.x + threadIdx.x; e < E; e += stride)
    atomicAdd(&cnt[dst[e]], 1);
}

// hierarchical scan: A = per-block reduce (1024 counts), B = scan block sums,
// C = per-block exclusive scan + writeback
__global__ __launch_bounds__(256) void scanA_k(const int* __restrict__ cnt,
                                               int* __restrict__ bsum, int N) {
  __shared__ int red[256];
  int tid = threadIdx.x;
  int i0 = blockIdx.x * 1024 + tid * 4;
  int s = 0;
  #pragma unroll
  for (int k = 0; k < 4; ++k) { int i = i0 + k; if (i < N) s += cnt[i]; }
  red[tid] = s;
  __syncthreads();
  for (int off = 128; off; off >>= 1) {
    if (tid < off) red[tid] += red[tid + off];
    __syncthreads();
  }
  if (tid == 0) bsum[blockIdx.x] = red[0];
}

__global__ __launch_bounds__(128) void scanB_k(const int* __restrict__ bsum,
                                               int* __restrict__ bbase, int nb) {
  __shared__ int buf[2][128];
  int tid = threadIdx.x;
  buf[0][tid] = (tid < nb) ? bsum[tid] : 0;
  __syncthreads();
  int pin = 0;
  for (int off = 1; off < 128; off <<= 1) {
    int x = buf[pin][tid];
    if (tid >= off) x += buf[pin][tid - off];
    buf[1 - pin][tid] = x;
    __syncthreads();
    pin = 1 - pin;
  }
  if (tid < nb) bbase[tid] = (tid == 0) ? 0 : buf[pin][tid - 1];
}

__global__ __launch_bounds__(256) void scanC_k(const int* __restrict__ cnt,
    const int* __restrict__ bbase, int* __restrict__ rp, int N, int E) {
  __shared__ int buf[2][256];
  int tid = threadIdx.x;
  int i0 = blockIdx.x * 1024 + tid * 4;
  int c[4]; int s = 0;
  #pragma unroll
  for (int k = 0; k < 4; ++k) { int i = i0 + k; c[k] = (i < N) ? cnt[i] : 0; s += c[k]; }
  buf[0][tid] = s;
  __syncthreads();
  int pin = 0;
  for (int off = 1; off < 256; off <<= 1) {
    int x = buf[pin][tid];
    if (tid >= off) x += buf[pin][tid - off];
    buf[1 - pin][tid] = x;
    __syncthreads();
    pin = 1 - pin;
  }
  int run = bbase[blockIdx.x] + buf[pin][tid] - s;  // exclusive prefix
  #pragma unroll
  for (int k = 0; k < 4; ++k) {
    int i = i0 + k;
    if (i < N) { rp[i] = run; run += c[k]; }
  }
  if (blockIdx.x == 0 && tid == 0) rp[N] = E;
}

// ---- pass A: bucket-append edges into CSR-bucket regions (dense writes) ----
// bucket b = dst>>6 covers nodes [64b,64b+64); its CSR span starts at rp[64b].
// payload packs src (26b) | (dst&63)<<26 ; weight as raw f32 bits.
__global__ void passA_k(const int* __restrict__ src, const int* __restrict__ dst,
                        const float* __restrict__ w, const int* __restrict__ rp,
                        int* __restrict__ bcnt, int2* __restrict__ tmp, int E) {
  int stride = gridDim.x * blockDim.x;
  for (int e = blockIdx.x * blockDim.x + threadIdx.x; e < E; e += stride) {
    int d = dst[e];
    int b = d >> 6;
    int off = atomicAdd(&bcnt[b], 1);
    int p = rp[b << 6] + off;
    tmp[p] = make_int2(src[e] | ((d & 63) << 26), __float_as_int(w[e]));
  }
}

// ---- pass B: within each bucket, order by node via LDS histogram (no global atomics) ----
__global__ __launch_bounds__(256) void passB_k(const int2* __restrict__ tmp,
    const int* __restrict__ rp, int2* __restrict__ epk, int N) {
  __shared__ int rps[65];
  __shared__ int cnt64[64];
  int b = blockIdx.x;
  int node0 = b << 6;
  int nA = min(64, N - node0);
  int tid = threadIdx.x;
  if (tid <= nA) rps[tid] = rp[node0 + tid];
  if (tid < 64) cnt64[tid] = 0;
  __syncthreads();
  int lo = rps[0], hi = rps[nA];
  for (int i = lo + tid; i < hi; i += 256) {
    int2 t = tmp[i];
    int dlo = (uint)t.x >> 26;
    int off = atomicAdd(&cnt64[dlo], 1);
    epk[rps[dlo] + off] = make_int2(t.x & 0x03ffffff, t.y);
  }
}

// ---------------- SpMM (pull, CSR by dst, bf16 gather) + initial-residual mix ----------------
// outbf[i,:] = bf16( 0.9 * sum_e w_e * h[src_e,:] + 0.1 * x0[i,:] )
// One node per wave; two 32-lane halves process alternating edges, 4 gathers in
// flight per half; each gather = full 128-col bf16 row, uint2 (4 bf16) per lane.
__global__ __launch_bounds__(256) void spmm_k(const int* __restrict__ rp,
    const int2* __restrict__ epk, const uint* __restrict__ hbf,
    const uint* __restrict__ x0bf, uint* __restrict__ outbf, int N) {
  int gw = (blockIdx.x * blockDim.x + threadIdx.x) >> 6;
  int lane = threadIdx.x & 63;
  if (gw >= N) return;
  int half = lane >> 5, l32 = lane & 31;
  int b = __builtin_amdgcn_readfirstlane(rp[gw]);
  int e = __builtin_amdgcn_readfirstlane(rp[gw + 1]);
  float4 acc = make_float4(0.f, 0.f, 0.f, 0.f);
  int j = b + half;
  for (; j + 6 < e; j += 8) {   // this half: edges j, j+2, j+4, j+6
    int2 e0 = epk[j], e1 = epk[j + 2], e2 = epk[j + 4], e3 = epk[j + 6];
    float w0 = __int_as_float(e0.y), w1 = __int_as_float(e1.y);
    float w2 = __int_as_float(e2.y), w3 = __int_as_float(e3.y);
    uint2 h0 = ((const uint2*)hbf)[(size_t)e0.x * 32 + l32];
    uint2 h1 = ((const uint2*)hbf)[(size_t)e1.x * 32 + l32];
    uint2 h2 = ((const uint2*)hbf)[(size_t)e2.x * 32 + l32];
    uint2 h3 = ((const uint2*)hbf)[(size_t)e3.x * 32 + l32];
    acc.x = fmaf(w0, bflo(h0.x), acc.x); acc.y = fmaf(w0, bfhi(h0.x), acc.y);
    acc.z = fmaf(w0, bflo(h0.y), acc.z); acc.w = fmaf(w0, bfhi(h0.y), acc.w);
    acc.x = fmaf(w1, bflo(h1.x), acc.x); acc.y = fmaf(w1, bfhi(h1.x), acc.y);
    acc.z = fmaf(w1, bflo(h1.y), acc.z); acc.w = fmaf(w1, bfhi(h1.y), acc.w);
    acc.x = fmaf(w2, bflo(h2.x), acc.x); acc.y = fmaf(w2, bfhi(h2.x), acc.y);
    acc.z = fmaf(w2, bflo(h2.y), acc.z); acc.w = fmaf(w2, bfhi(h2.y), acc.w);
    acc.x = fmaf(w3, bflo(h3.x), acc.x); acc.y = fmaf(w3, bfhi(h3.x), acc.y);
    acc.z = fmaf(w3, bflo(h3.y), acc.z); acc.w = fmaf(w3, bfhi(h3.y), acc.w);
  }
  for (; j < e; j += 2) {
    int2 e0 = epk[j];
    float w0 = __int_as_float(e0.y);
    uint2 h0 = ((const uint2*)hbf)[(size_t)e0.x * 32 + l32];
    acc.x = fmaf(w0, bflo(h0.x), acc.x); acc.y = fmaf(w0, bfhi(h0.x), acc.y);
    acc.z = fmaf(w0, bflo(h0.y), acc.z); acc.w = fmaf(w0, bfhi(h0.y), acc.w);
  }
  acc.x += __shfl_xor(acc.x, 32);
  acc.y += __shfl_xor(acc.y, 32);
  acc.z += __shfl_xor(acc.z, 32);
  acc.w += __shfl_xor(acc.w, 32);
  if (half == 0) {
    uint2 xv = ((const uint2*)x0bf)[(size_t)gw * 32 + l32];
    float ox = 0.9f * acc.x + 0.1f * bflo(xv.x);
    float oy = 0.9f * acc.y + 0.1f * bfhi(xv.x);
    float oz = 0.9f * acc.z + 0.1f * bflo(xv.y);
    float ow = 0.9f * acc.w + 0.1f * bfhi(xv.y);
    ((uint2*)outbf)[(size_t)gw * 32 + l32] = make_uint2(packbf2(ox, oy), packbf2(oz, ow));
  }
}

// ---------------- tiled dense GEMM: 128x128 tile, BK=32, 8x8 per thread ----------------
// MODE 0 (proj, ABF=0): y = relu(in@W + bias); bf16 -> outbf (h), outbf2 (x0)
// MODE 1 (conv, ABF=1): y = relu(cin*in + cw*(in@W)); bf16 -> outbf
// MODE 2 (final, ABF=1): y = log_softmax(in@W + bias); f32 -> outf
template<int MODE, int ABF>
__global__ __launch_bounds__(256, 4) void gemm_tiled(const void* __restrict__ inv,
    const float* __restrict__ W, const float* __restrict__ bias,
    float* __restrict__ outf, uint* __restrict__ outbf, uint* __restrict__ outbf2,
    float cin, float cw, int N) {
  __shared__ float As[32][132];   // k-major, transposed A tile (+pad)
  __shared__ float Ws[32][132];   // k-major W tile (+pad)
  const float* inf = (const float*)inv;
  const uint*  inb = (const uint*)inv;
  int tid = threadIdx.x;
  int tx = tid & 15;              // col group
  int ty = tid >> 4;              // row group
  int rbase = blockIdx.x * 128;

  float4 acc[8][2];
  #pragma unroll
  for (int i = 0; i < 8; ++i) {
    acc[i][0] = make_float4(0.f, 0.f, 0.f, 0.f);
    acc[i][1] = make_float4(0.f, 0.f, 0.f, 0.f);
  }

  for (int kt = 0; kt < 4; ++kt) {
    if (ABF) {
      #pragma unroll
      for (int i = 0; i < 2; ++i) {
        int f = tid + 256 * i;
        int r = f >> 2, c = f & 3;
        int grow = rbase + r;
        uint4 u = make_uint4(0u, 0u, 0u, 0u);
        if (grow < N) u = *(const uint4*)&inb[(size_t)grow * 64 + kt * 16 + c * 4];
        As[c * 8 + 0][r] = bflo(u.x); As[c * 8 + 1][r] = bfhi(u.x);
        As[c * 8 + 2][r] = bflo(u.y); As[c * 8 + 3][r] = bfhi(u.y);
        As[c * 8 + 4][r] = bflo(u.z); As[c * 8 + 5][r] = bfhi(u.z);
        As[c * 8 + 6][r] = bflo(u.w); As[c * 8 + 7][r] = bfhi(u.w);
      }
    } else {
      #pragma unroll
      for (int i = 0; i < 4; ++i) {
        int f = tid + 256 * i;
        int r = f >> 3, c = f & 7;
        int grow = rbase + r;
        float4 v = make_float4(0.f, 0.f, 0.f, 0.f);
        if (grow < N) v = *(const float4*)&inf[(size_t)grow * 128 + kt * 32 + c * 4];
        As[c * 4 + 0][r] = v.x;
        As[c * 4 + 1][r] = v.y;
        As[c * 4 + 2][r] = v.z;
        As[c * 4 + 3][r] = v.w;
      }
    }
    #pragma unroll
    for (int i = 0; i < 4; ++i) {
      int f = tid + 256 * i;
      int k = f >> 5, n4 = f & 31;
      *(float4*)&Ws[k][n4 * 4] = *(const float4*)&W[(size_t)(kt * 32 + k) * 128 + n4 * 4];
    }
    __syncthreads();
    #pragma unroll 8
    for (int k = 0; k < 32; ++k) {
      float4 al = *(const float4*)&As[k][4 * ty];
      float4 ah = *(const float4*)&As[k][64 + 4 * ty];
      float4 wl = *(const float4*)&Ws[k][4 * tx];
      float4 wh = *(const float4*)&Ws[k][64 + 4 * tx];
      float a_[8] = {al.x, al.y, al.z, al.w, ah.x, ah.y, ah.z, ah.w};
      #pragma unroll
      for (int i = 0; i < 8; ++i) {
        acc[i][0].x = fmaf(a_[i], wl.x, acc[i][0].x);
        acc[i][0].y = fmaf(a_[i], wl.y, acc[i][0].y);
        acc[i][0].z = fmaf(a_[i], wl.z, acc[i][0].z);
        acc[i][0].w = fmaf(a_[i], wl.w, acc[i][0].w);
        acc[i][1].x = fmaf(a_[i], wh.x, acc[i][1].x);
        acc[i][1].y = fmaf(a_[i], wh.y, acc[i][1].y);
        acc[i][1].z = fmaf(a_[i], wh.z, acc[i][1].z);
        acc[i][1].w = fmaf(a_[i], wh.w, acc[i][1].w);
      }
    }
    __syncthreads();
  }

  float4 bl = make_float4(0.f, 0.f, 0.f, 0.f), bh = bl;
  if (MODE != 1) {
    bl = *(const float4*)&bias[4 * tx];
    bh = *(const float4*)&bias[64 + 4 * tx];
  }
  #pragma unroll
  for (int i = 0; i < 8; ++i) {
    int r = rbase + ((i < 4) ? (4 * ty + i) : (64 + 4 * ty + (i - 4)));
    bool valid = (r < N);
    float4 y0 = acc[i][0], y1 = acc[i][1];
    if (MODE == 1) {
      float4 i0 = make_float4(0.f,0.f,0.f,0.f), i1 = i0;
      if (valid) {
        uint2 a0 = ((const uint2*)inb)[(size_t)r * 32 + tx];
        uint2 a1 = ((const uint2*)inb)[(size_t)r * 32 + 16 + tx];
        i0 = make_float4(bflo(a0.x), bfhi(a0.x), bflo(a0.y), bfhi(a0.y));
        i1 = make_float4(bflo(a1.x), bfhi(a1.x), bflo(a1.y), bfhi(a1.y));
      }
      y0.x = fmaxf(cin * i0.x + cw * y0.x, 0.f);
      y0.y = fmaxf(cin * i0.y + cw * y0.y, 0.f);
      y0.z = fmaxf(cin * i0.z + cw * y0.z, 0.f);
      y0.w = fmaxf(cin * i0.w + cw * y0.w, 0.f);
      y1.x = fmaxf(cin * i1.x + cw * y1.x, 0.f);
      y1.y = fmaxf(cin * i1.y + cw * y1.y, 0.f);
      y1.z = fmaxf(cin * i1.z + cw * y1.z, 0.f);
      y1.w = fmaxf(cin * i1.w + cw * y1.w, 0.f);
    } else {
      y0.x += bl.x; y0.y += bl.y; y0.z += bl.z; y0.w += bl.w;
      y1.x += bh.x; y1.y += bh.y; y1.z += bh.z; y1.w += bh.w;
      if (MODE == 0) {
        y0.x = fmaxf(y0.x, 0.f); y0.y = fmaxf(y0.y, 0.f);
        y0.z = fmaxf(y0.z, 0.f); y0.w = fmaxf(y0.w, 0.f);
        y1.x = fmaxf(y1.x, 0.f); y1.y = fmaxf(y1.y, 0.f);
        y1.z = fmaxf(y1.z, 0.f); y1.w = fmaxf(y1.w, 0.f);
      }
    }
    if (MODE == 2) {
      float m = fmaxf(fmaxf(fmaxf(y0.x, y0.y), fmaxf(y0.z, y0.w)),
                      fmaxf(fmaxf(y1.x, y1.y), fmaxf(y1.z, y1.w)));
      #pragma unroll
      for (int off = 1; off <= 8; off <<= 1) m = fmaxf(m, __shfl_xor(m, off));
      float s = expf(y0.x - m) + expf(y0.y - m) + expf(y0.z - m) + expf(y0.w - m)
              + expf(y1.x - m) + expf(y1.y - m) + expf(y1.z - m) + expf(y1.w - m);
      #pragma unroll
      for (int off = 1; off <= 8; off <<= 1) s += __shfl_xor(s, off);
      float lg = m + logf(s);
      y0.x -= lg; y0.y -= lg; y0.z -= lg; y0.w -= lg;
      y1.x -= lg; y1.y -= lg; y1.z -= lg; y1.w -= lg;
    }
    if (valid) {
      if (MODE == 2) {
        *(float4*)&outf[(size_t)r * 128 + 4 * tx] = y0;
        *(float4*)&outf[(size_t)r * 128 + 64 + 4 * tx] = y1;
      } else {
        uint2 u0 = make_uint2(packbf2(y0.x, y0.y), packbf2(y0.z, y0.w));
        uint2 u1 = make_uint2(packbf2(y1.x, y1.y), packbf2(y1.z, y1.w));
        ((uint2*)outbf)[(size_t)r * 32 + tx] = u0;
        ((uint2*)outbf)[(size_t)r * 32 + 16 + tx] = u1;
        if (MODE == 0) {
          ((uint2*)outbf2)[(size_t)r * 32 + tx] = u0;
          ((uint2*)outbf2)[(size_t)r * 32 + 16 + tx] = u1;
        }
      }
    }
  }
}

extern "C" void kernel_launch(void* const* d_in, const int* in_sizes, int n_in,
                              void* d_out, int out_size, void* d_ws, size_t ws_size,
                              hipStream_t stream) {
  const float* x     = (const float*)d_in[0];
  const int*   esrc  = (const int*)d_in[1];
  const int*   edst  = (const int*)d_in[2];
  const float* ew    = (const float*)d_in[3];
  const float* W0    = (const float*)d_in[4];
  const float* b0    = (const float*)d_in[5];
  const float* W1    = (const float*)d_in[6];
  const float* b1    = (const float*)d_in[7];
  const float* convW = (const float*)d_in[8];
  int N = in_sizes[0] / 128;
  int E = in_sizes[1];
  float* outp = (float*)d_out;

  char* ws = (char*)d_ws;
  size_t off = 0;
  auto alloc = [&](size_t bytes) {
    void* p = ws + off;
    off += (bytes + 255) & ~(size_t)255;
    return p;
  };
  int nBuk = (N + 63) / 64;
  uint*  hbf   = (uint*)alloc((size_t)N * 128 * 2);
  uint*  x0bf  = (uint*)alloc((size_t)N * 128 * 2);
  uint*  bufB  = (uint*)alloc((size_t)N * 128 * 2);   // spmm out (bf16)
  uint*  bufA  = (uint*)alloc((size_t)N * 128 * 2);   // final-GEMM input (bf16)
  int*   rp    = (int*)alloc((size_t)(N + 1) * 4);
  int*   cnt   = (int*)alloc((size_t)N * 4);
  int*   bcnt  = (int*)alloc((size_t)nBuk * 4);
  int2*  tmp   = (int2*)alloc((size_t)E * 8);
  int2*  epk   = (int2*)alloc((size_t)E * 8);
  int nbScan = (N + 1023) / 1024;
  int*   bsum  = (int*)alloc((size_t)nbScan * 4);
  int*   bbase = (int*)alloc((size_t)nbScan * 4);

  // ---- CSR build ----
  hipMemsetAsync(cnt, 0, (size_t)N * 4, stream);
  hipMemsetAsync(bcnt, 0, (size_t)nBuk * 4, stream);
  hist_k<<<2048, 256, 0, stream>>>(edst, cnt, E);
  scanA_k<<<nbScan, 256, 0, stream>>>(cnt, bsum, N);
  scanB_k<<<1, 128, 0, stream>>>(bsum, bbase, nbScan);
  scanC_k<<<nbScan, 256, 0, stream>>>(cnt, bbase, rp, N, E);
  passA_k<<<2048, 256, 0, stream>>>(esrc, edst, ew, rp, bcnt, tmp, E);
  passB_k<<<nBuk, 256, 0, stream>>>(tmp, rp, epk, N);

  int gemmBlocks = (N + 127) / 128;
  int spmmBlocks = (N + 3) / 4;

  // ---- input projection: h = relu(x@W0 + b0) -> hbf, x0bf (bf16) ----
  gemm_tiled<0, 0><<<gemmBlocks, 256, 0, stream>>>(x, W0, b0, nullptr, hbf, x0bf, 0.f, 1.f, N);

  // ---- 4 GCNII layers ----
  for (int l = 0; l < 4; ++l) {
    float beta = logf(0.5f / (float)(l + 1) + 1.f);
    spmm_k<<<spmmBlocks, 256, 0, stream>>>(rp, epk, hbf, x0bf, bufB, N);
    gemm_tiled<1, 1><<<gemmBlocks, 256, 0, stream>>>(
        bufB, convW + (size_t)l * 128 * 128, nullptr,
        nullptr, (l == 3) ? bufA : hbf, nullptr,
        1.f - beta, beta, N);
  }

  // ---- final: logits + log_softmax ----
  gemm_tiled<2, 1><<<gemmBlocks, 256, 0, stream>>>(bufA, W1, b1, outp, nullptr, nullptr, 0.f, 1.f, N);
}

// Round 7
// 760.001 us; speedup vs baseline: 1.2185x; 1.2185x over previous
//
#include <hip/hip_runtime.h>
#include <math.h>

typedef unsigned int uint;

__device__ inline uint packbf2(float a, float b) {
  uint ua = __float_as_uint(a), ub = __float_as_uint(b);
  ua = (ua + 0x7fffu + ((ua >> 16) & 1u)) >> 16;
  ub = (ub + 0x7fffu + ((ub >> 16) & 1u)) & 0xffff0000u;
  return ua | ub;
}
__device__ inline float bflo(uint u) { return __uint_as_float(u << 16); }
__device__ inline float bfhi(uint u) { return __uint_as_float(u & 0xffff0000u); }

// ---------------- CSR build ----------------
__global__ void hist_k(const int* __restrict__ dst, int* __restrict__ cnt, int E) {
  int tid = blockIdx.x * blockDim.x + threadIdx.x;
  int stride4 = gridDim.x * blockDim.x * 4;
  for (int base = tid * 4; base + 3 < E; base += stride4) {
    int4 d = *(const int4*)&dst[base];
    atomicAdd(&cnt[d.x], 1);
    atomicAdd(&cnt[d.y], 1);
    atomicAdd(&cnt[d.z], 1);
    atomicAdd(&cnt[d.w], 1);
  }
  // tail
  int tail0 = (E & ~3);
  int e = tail0 + tid;
  if (e < E) atomicAdd(&cnt[dst[e]], 1);
}

// hierarchical scan: A = per-block reduce (1024 counts), B = scan block sums,
// C = per-block exclusive scan + writeback
__global__ __launch_bounds__(256) void scanA_k(const int* __restrict__ cnt,
                                               int* __restrict__ bsum, int N) {
  __shared__ int red[256];
  int tid = threadIdx.x;
  int i0 = blockIdx.x * 1024 + tid * 4;
  int s = 0;
  #pragma unroll
  for (int k = 0; k < 4; ++k) { int i = i0 + k; if (i < N) s += cnt[i]; }
  red[tid] = s;
  __syncthreads();
  for (int off = 128; off; off >>= 1) {
    if (tid < off) red[tid] += red[tid + off];
    __syncthreads();
  }
  if (tid == 0) bsum[blockIdx.x] = red[0];
}

__global__ __launch_bounds__(128) void scanB_k(const int* __restrict__ bsum,
                                               int* __restrict__ bbase, int nb) {
  __shared__ int buf[2][128];
  int tid = threadIdx.x;
  buf[0][tid] = (tid < nb) ? bsum[tid] : 0;
  __syncthreads();
  int pin = 0;
  for (int off = 1; off < 128; off <<= 1) {
    int x = buf[pin][tid];
    if (tid >= off) x += buf[pin][tid - off];
    buf[1 - pin][tid] = x;
    __syncthreads();
    pin = 1 - pin;
  }
  if (tid < nb) bbase[tid] = (tid == 0) ? 0 : buf[pin][tid - 1];
}

__global__ __launch_bounds__(256) void scanC_k(const int* __restrict__ cnt,
    const int* __restrict__ bbase, int* __restrict__ rp, int N, int E) {
  __shared__ int buf[2][256];
  int tid = threadIdx.x;
  int i0 = blockIdx.x * 1024 + tid * 4;
  int c[4]; int s = 0;
  #pragma unroll
  for (int k = 0; k < 4; ++k) { int i = i0 + k; c[k] = (i < N) ? cnt[i] : 0; s += c[k]; }
  buf[0][tid] = s;
  __syncthreads();
  int pin = 0;
  for (int off = 1; off < 256; off <<= 1) {
    int x = buf[pin][tid];
    if (tid >= off) x += buf[pin][tid - off];
    buf[1 - pin][tid] = x;
    __syncthreads();
    pin = 1 - pin;
  }
  int run = bbase[blockIdx.x] + buf[pin][tid] - s;  // exclusive prefix
  #pragma unroll
  for (int k = 0; k < 4; ++k) {
    int i = i0 + k;
    if (i < N) { rp[i] = run; run += c[k]; }
  }
  if (blockIdx.x == 0 && tid == 0) rp[N] = E;
}

// scatter into per-node CSR slots; consumes hist counts via atomic decrement
// (off = cnt[d]-1 .. 0), so no second memset/count pass is needed.
__global__ void scatter_k(const int* __restrict__ src, const int* __restrict__ dst,
                          const float* __restrict__ w, const int* __restrict__ rp,
                          int* __restrict__ cnt, int2* __restrict__ epk, int E) {
  int stride = gridDim.x * blockDim.x;
  for (int e = blockIdx.x * blockDim.x + threadIdx.x; e < E; e += stride) {
    int d = dst[e];
    int off = atomicAdd(&cnt[d], -1) - 1;
    epk[rp[d] + off] = make_int2(src[e], __float_as_int(w[e]));
  }
}

// ---------------- SpMM (pull, CSR by dst, bf16 gather) + initial-residual mix ----------------
// outbf[i,:] = bf16( 0.9 * sum_e w_e * h[src_e,:] + 0.1 * x0[i,:] )
// One node per wave; FOUR 16-lane groups process every-4th edge; each group
// gathers a full 128-col bf16 row as uint4 (8 bf16, 16B) per lane; unroll 2
// -> 8 gathers in flight per wave. Combine via 2-stage shfl_xor.
__global__ __launch_bounds__(256) void spmm_k(const int* __restrict__ rp,
    const int2* __restrict__ epk, const uint* __restrict__ hbf,
    const uint* __restrict__ x0bf, uint* __restrict__ outbf, int N) {
  int gw = (blockIdx.x * blockDim.x + threadIdx.x) >> 6;
  int lane = threadIdx.x & 63;
  if (gw >= N) return;
  int grp = lane >> 4, l16 = lane & 15;
  int b = __builtin_amdgcn_readfirstlane(rp[gw]);
  int e = __builtin_amdgcn_readfirstlane(rp[gw + 1]);
  float a0 = 0.f, a1 = 0.f, a2 = 0.f, a3 = 0.f;
  float a4 = 0.f, a5 = 0.f, a6 = 0.f, a7 = 0.f;
  int j = b + grp;
  for (; j + 4 < e; j += 8) {   // this group: edges j, j+4
    int2 e0 = epk[j], e1 = epk[j + 4];
    float w0 = __int_as_float(e0.y), w1 = __int_as_float(e1.y);
    uint4 h0 = ((const uint4*)hbf)[(size_t)e0.x * 16 + l16];
    uint4 h1 = ((const uint4*)hbf)[(size_t)e1.x * 16 + l16];
    a0 = fmaf(w0, bflo(h0.x), a0); a1 = fmaf(w0, bfhi(h0.x), a1);
    a2 = fmaf(w0, bflo(h0.y), a2); a3 = fmaf(w0, bfhi(h0.y), a3);
    a4 = fmaf(w0, bflo(h0.z), a4); a5 = fmaf(w0, bfhi(h0.z), a5);
    a6 = fmaf(w0, bflo(h0.w), a6); a7 = fmaf(w0, bfhi(h0.w), a7);
    a0 = fmaf(w1, bflo(h1.x), a0); a1 = fmaf(w1, bfhi(h1.x), a1);
    a2 = fmaf(w1, bflo(h1.y), a2); a3 = fmaf(w1, bfhi(h1.y), a3);
    a4 = fmaf(w1, bflo(h1.z), a4); a5 = fmaf(w1, bfhi(h1.z), a5);
    a6 = fmaf(w1, bflo(h1.w), a6); a7 = fmaf(w1, bfhi(h1.w), a7);
  }
  for (; j < e; j += 4) {
    int2 e0 = epk[j];
    float w0 = __int_as_float(e0.y);
    uint4 h0 = ((const uint4*)hbf)[(size_t)e0.x * 16 + l16];
    a0 = fmaf(w0, bflo(h0.x), a0); a1 = fmaf(w0, bfhi(h0.x), a1);
    a2 = fmaf(w0, bflo(h0.y), a2); a3 = fmaf(w0, bfhi(h0.y), a3);
    a4 = fmaf(w0, bflo(h0.z), a4); a5 = fmaf(w0, bfhi(h0.z), a5);
    a6 = fmaf(w0, bflo(h0.w), a6); a7 = fmaf(w0, bfhi(h0.w), a7);
  }
  // combine the 4 groups (lanes l16, l16+16, l16+32, l16+48)
  a0 += __shfl_xor(a0, 16); a1 += __shfl_xor(a1, 16);
  a2 += __shfl_xor(a2, 16); a3 += __shfl_xor(a3, 16);
  a4 += __shfl_xor(a4, 16); a5 += __shfl_xor(a5, 16);
  a6 += __shfl_xor(a6, 16); a7 += __shfl_xor(a7, 16);
  a0 += __shfl_xor(a0, 32); a1 += __shfl_xor(a1, 32);
  a2 += __shfl_xor(a2, 32); a3 += __shfl_xor(a3, 32);
  a4 += __shfl_xor(a4, 32); a5 += __shfl_xor(a5, 32);
  a6 += __shfl_xor(a6, 32); a7 += __shfl_xor(a7, 32);
  if (grp == 0) {
    uint4 xv = ((const uint4*)x0bf)[(size_t)gw * 16 + l16];
    float o0 = 0.9f * a0 + 0.1f * bflo(xv.x);
    float o1 = 0.9f * a1 + 0.1f * bfhi(xv.x);
    float o2 = 0.9f * a2 + 0.1f * bflo(xv.y);
    float o3 = 0.9f * a3 + 0.1f * bfhi(xv.y);
    float o4 = 0.9f * a4 + 0.1f * bflo(xv.z);
    float o5 = 0.9f * a5 + 0.1f * bfhi(xv.z);
    float o6 = 0.9f * a6 + 0.1f * bflo(xv.w);
    float o7 = 0.9f * a7 + 0.1f * bfhi(xv.w);
    uint4 u;
    u.x = packbf2(o0, o1); u.y = packbf2(o2, o3);
    u.z = packbf2(o4, o5); u.w = packbf2(o6, o7);
    ((uint4*)outbf)[(size_t)gw * 16 + l16] = u;
  }
}

// ---------------- tiled dense GEMM: 128x128 tile, BK=32, 8x8 per thread ----------------
// MODE 0 (proj, ABF=0): y = relu(in@W + bias); bf16 -> outbf (h), outbf2 (x0)
// MODE 1 (conv, ABF=1): y = relu(cin*in + cw*(in@W)); bf16 -> outbf
// MODE 2 (final, ABF=1): y = log_softmax(in@W + bias); f32 -> outf
template<int MODE, int ABF>
__global__ __launch_bounds__(256, 4) void gemm_tiled(const void* __restrict__ inv,
    const float* __restrict__ W, const float* __restrict__ bias,
    float* __restrict__ outf, uint* __restrict__ outbf, uint* __restrict__ outbf2,
    float cin, float cw, int N) {
  __shared__ float As[32][132];   // k-major, transposed A tile (+pad)
  __shared__ float Ws[32][132];   // k-major W tile (+pad)
  const float* inf = (const float*)inv;
  const uint*  inb = (const uint*)inv;
  int tid = threadIdx.x;
  int tx = tid & 15;              // col group
  int ty = tid >> 4;              // row group
  int rbase = blockIdx.x * 128;

  float4 acc[8][2];
  #pragma unroll
  for (int i = 0; i < 8; ++i) {
    acc[i][0] = make_float4(0.f, 0.f, 0.f, 0.f);
    acc[i][1] = make_float4(0.f, 0.f, 0.f, 0.f);
  }

  for (int kt = 0; kt < 4; ++kt) {
    if (ABF) {
      #pragma unroll
      for (int i = 0; i < 2; ++i) {
        int f = tid + 256 * i;
        int r = f >> 2, c = f & 3;
        int grow = rbase + r;
        uint4 u = make_uint4(0u, 0u, 0u, 0u);
        if (grow < N) u = *(const uint4*)&inb[(size_t)grow * 64 + kt * 16 + c * 4];
        As[c * 8 + 0][r] = bflo(u.x); As[c * 8 + 1][r] = bfhi(u.x);
        As[c * 8 + 2][r] = bflo(u.y); As[c * 8 + 3][r] = bfhi(u.y);
        As[c * 8 + 4][r] = bflo(u.z); As[c * 8 + 5][r] = bfhi(u.z);
        As[c * 8 + 6][r] = bflo(u.w); As[c * 8 + 7][r] = bfhi(u.w);
      }
    } else {
      #pragma unroll
      for (int i = 0; i < 4; ++i) {
        int f = tid + 256 * i;
        int r = f >> 3, c = f & 7;
        int grow = rbase + r;
        float4 v = make_float4(0.f, 0.f, 0.f, 0.f);
        if (grow < N) v = *(const float4*)&inf[(size_t)grow * 128 + kt * 32 + c * 4];
        As[c * 4 + 0][r] = v.x;
        As[c * 4 + 1][r] = v.y;
        As[c * 4 + 2][r] = v.z;
        As[c * 4 + 3][r] = v.w;
      }
    }
    #pragma unroll
    for (int i = 0; i < 4; ++i) {
      int f = tid + 256 * i;
      int k = f >> 5, n4 = f & 31;
      *(float4*)&Ws[k][n4 * 4] = *(const float4*)&W[(size_t)(kt * 32 + k) * 128 + n4 * 4];
    }
    __syncthreads();
    #pragma unroll 8
    for (int k = 0; k < 32; ++k) {
      float4 al = *(const float4*)&As[k][4 * ty];
      float4 ah = *(const float4*)&As[k][64 + 4 * ty];
      float4 wl = *(const float4*)&Ws[k][4 * tx];
      float4 wh = *(const float4*)&Ws[k][64 + 4 * tx];
      float a_[8] = {al.x, al.y, al.z, al.w, ah.x, ah.y, ah.z, ah.w};
      #pragma unroll
      for (int i = 0; i < 8; ++i) {
        acc[i][0].x = fmaf(a_[i], wl.x, acc[i][0].x);
        acc[i][0].y = fmaf(a_[i], wl.y, acc[i][0].y);
        acc[i][0].z = fmaf(a_[i], wl.z, acc[i][0].z);
        acc[i][0].w = fmaf(a_[i], wl.w, acc[i][0].w);
        acc[i][1].x = fmaf(a_[i], wh.x, acc[i][1].x);
        acc[i][1].y = fmaf(a_[i], wh.y, acc[i][1].y);
        acc[i][1].z = fmaf(a_[i], wh.z, acc[i][1].z);
        acc[i][1].w = fmaf(a_[i], wh.w, acc[i][1].w);
      }
    }
    __syncthreads();
  }

  float4 bl = make_float4(0.f, 0.f, 0.f, 0.f), bh = bl;
  if (MODE != 1) {
    bl = *(const float4*)&bias[4 * tx];
    bh = *(const float4*)&bias[64 + 4 * tx];
  }
  #pragma unroll
  for (int i = 0; i < 8; ++i) {
    int r = rbase + ((i < 4) ? (4 * ty + i) : (64 + 4 * ty + (i - 4)));
    bool valid = (r < N);
    float4 y0 = acc[i][0], y1 = acc[i][1];
    if (MODE == 1) {
      float4 i0 = make_float4(0.f,0.f,0.f,0.f), i1 = i0;
      if (valid) {
        uint2 c0 = ((const uint2*)inb)[(size_t)r * 32 + tx];
        uint2 c1 = ((const uint2*)inb)[(size_t)r * 32 + 16 + tx];
        i0 = make_float4(bflo(c0.x), bfhi(c0.x), bflo(c0.y), bfhi(c0.y));
        i1 = make_float4(bflo(c1.x), bfhi(c1.x), bflo(c1.y), bfhi(c1.y));
      }
      y0.x = fmaxf(cin * i0.x + cw * y0.x, 0.f);
      y0.y = fmaxf(cin * i0.y + cw * y0.y, 0.f);
      y0.z = fmaxf(cin * i0.z + cw * y0.z, 0.f);
      y0.w = fmaxf(cin * i0.w + cw * y0.w, 0.f);
      y1.x = fmaxf(cin * i1.x + cw * y1.x, 0.f);
      y1.y = fmaxf(cin * i1.y + cw * y1.y, 0.f);
      y1.z = fmaxf(cin * i1.z + cw * y1.z, 0.f);
      y1.w = fmaxf(cin * i1.w + cw * y1.w, 0.f);
    } else {
      y0.x += bl.x; y0.y += bl.y; y0.z += bl.z; y0.w += bl.w;
      y1.x += bh.x; y1.y += bh.y; y1.z += bh.z; y1.w += bh.w;
      if (MODE == 0) {
        y0.x = fmaxf(y0.x, 0.f); y0.y = fmaxf(y0.y, 0.f);
        y0.z = fmaxf(y0.z, 0.f); y0.w = fmaxf(y0.w, 0.f);
        y1.x = fmaxf(y1.x, 0.f); y1.y = fmaxf(y1.y, 0.f);
        y1.z = fmaxf(y1.z, 0.f); y1.w = fmaxf(y1.w, 0.f);
      }
    }
    if (MODE == 2) {
      float m = fmaxf(fmaxf(fmaxf(y0.x, y0.y), fmaxf(y0.z, y0.w)),
                      fmaxf(fmaxf(y1.x, y1.y), fmaxf(y1.z, y1.w)));
      #pragma unroll
      for (int off = 1; off <= 8; off <<= 1) m = fmaxf(m, __shfl_xor(m, off));
      float s = expf(y0.x - m) + expf(y0.y - m) + expf(y0.z - m) + expf(y0.w - m)
              + expf(y1.x - m) + expf(y1.y - m) + expf(y1.z - m) + expf(y1.w - m);
      #pragma unroll
      for (int off = 1; off <= 8; off <<= 1) s += __shfl_xor(s, off);
      float lg = m + logf(s);
      y0.x -= lg; y0.y -= lg; y0.z -= lg; y0.w -= lg;
      y1.x -= lg; y1.y -= lg; y1.z -= lg; y1.w -= lg;
    }
    if (valid) {
      if (MODE == 2) {
        *(float4*)&outf[(size_t)r * 128 + 4 * tx] = y0;
        *(float4*)&outf[(size_t)r * 128 + 64 + 4 * tx] = y1;
      } else {
        uint2 u0 = make_uint2(packbf2(y0.x, y0.y), packbf2(y0.z, y0.w));
        uint2 u1 = make_uint2(packbf2(y1.x, y1.y), packbf2(y1.z, y1.w));
        ((uint2*)outbf)[(size_t)r * 32 + tx] = u0;
        ((uint2*)outbf)[(size_t)r * 32 + 16 + tx] = u1;
        if (MODE == 0) {
          ((uint2*)outbf2)[(size_t)r * 32 + tx] = u0;
          ((uint2*)outbf2)[(size_t)r * 32 + 16 + tx] = u1;
        }
      }
    }
  }
}

extern "C" void kernel_launch(void* const* d_in, const int* in_sizes, int n_in,
                              void* d_out, int out_size, void* d_ws, size_t ws_size,
                              hipStream_t stream) {
  const float* x     = (const float*)d_in[0];
  const int*   esrc  = (const int*)d_in[1];
  const int*   edst  = (const int*)d_in[2];
  const float* ew    = (const float*)d_in[3];
  const float* W0    = (const float*)d_in[4];
  const float* b0    = (const float*)d_in[5];
  const float* W1    = (const float*)d_in[6];
  const float* b1    = (const float*)d_in[7];
  const float* convW = (const float*)d_in[8];
  int N = in_sizes[0] / 128;
  int E = in_sizes[1];
  float* outp = (float*)d_out;

  char* ws = (char*)d_ws;
  size_t off = 0;
  auto alloc = [&](size_t bytes) {
    void* p = ws + off;
    off += (bytes + 255) & ~(size_t)255;
    return p;
  };
  uint*  hbf   = (uint*)alloc((size_t)N * 128 * 2);
  uint*  x0bf  = (uint*)alloc((size_t)N * 128 * 2);
  uint*  bufB  = (uint*)alloc((size_t)N * 128 * 2);   // spmm out (bf16)
  uint*  bufA  = (uint*)alloc((size_t)N * 128 * 2);   // final-GEMM input (bf16)
  int*   rp    = (int*)alloc((size_t)(N + 1) * 4);
  int*   cnt   = (int*)alloc((size_t)N * 4);
  int2*  epk   = (int2*)alloc((size_t)E * 8);
  int nbScan = (N + 1023) / 1024;
  int*   bsum  = (int*)alloc((size_t)nbScan * 4);
  int*   bbase = (int*)alloc((size_t)nbScan * 4);

  // ---- CSR build ----
  hipMemsetAsync(cnt, 0, (size_t)N * 4, stream);
  hist_k<<<2048, 256, 0, stream>>>(edst, cnt, E);
  scanA_k<<<nbScan, 256, 0, stream>>>(cnt, bsum, N);
  scanB_k<<<1, 128, 0, stream>>>(bsum, bbase, nbScan);
  scanC_k<<<nbScan, 256, 0, stream>>>(cnt, bbase, rp, N, E);
  // scatter consumes cnt (atomic decrement), so no re-zeroing needed
  scatter_k<<<2048, 256, 0, stream>>>(esrc, edst, ew, rp, cnt, epk, E);

  int gemmBlocks = (N + 127) / 128;
  int spmmBlocks = (N + 3) / 4;

  // ---- input projection: h = relu(x@W0 + b0) -> hbf, x0bf (bf16) ----
  gemm_tiled<0, 0><<<gemmBlocks, 256, 0, stream>>>(x, W0, b0, nullptr, hbf, x0bf, 0.f, 1.f, N);

  // ---- 4 GCNII layers ----
  for (int l = 0; l < 4; ++l) {
    float beta = logf(0.5f / (float)(l + 1) + 1.f);
    spmm_k<<<spmmBlocks, 256, 0, stream>>>(rp, epk, hbf, x0bf, bufB, N);
    gemm_tiled<1, 1><<<gemmBlocks, 256, 0, stream>>>(
        bufB, convW + (size_t)l * 128 * 128, nullptr,
        nullptr, (l == 3) ? bufA : hbf, nullptr,
        1.f - beta, beta, N);
  }

  // ---- final: logits + log_softmax ----
  gemm_tiled<2, 1><<<gemmBlocks, 256, 0, stream>>>(bufA, W1, b1, outp, nullptr, nullptr, 0.f, 1.f, N);
}

// Round 8
// 595.955 us; speedup vs baseline: 1.5539x; 1.2753x over previous
//
#include <hip/hip_runtime.h>
#include <math.h>

typedef unsigned int uint;
typedef unsigned short ushort;
using bf8   = __attribute__((ext_vector_type(8))) short;   // 8 bf16 (4 VGPRs)
using f32x4 = __attribute__((ext_vector_type(4))) float;   // 4 fp32

__device__ inline ushort f2bf(float f) {
  uint u = __float_as_uint(f);
  return (ushort)((u + 0x7fffu + ((u >> 16) & 1u)) >> 16);
}
__device__ inline float bf2f(ushort s) { return __uint_as_float(((uint)s) << 16); }
__device__ inline uint packbf2(float a, float b) {
  uint ua = __float_as_uint(a), ub = __float_as_uint(b);
  ua = (ua + 0x7fffu + ((ua >> 16) & 1u)) >> 16;
  ub = (ub + 0x7fffu + ((ub >> 16) & 1u)) & 0xffff0000u;
  return ua | ub;
}
__device__ inline float bflo(uint u) { return __uint_as_float(u << 16); }
__device__ inline float bfhi(uint u) { return __uint_as_float(u & 0xffff0000u); }

// ---------------- CSR build ----------------
__global__ void hist_k(const int* __restrict__ dst, int* __restrict__ cnt, int E) {
  int tid = blockIdx.x * blockDim.x + threadIdx.x;
  int stride4 = gridDim.x * blockDim.x * 4;
  for (int base = tid * 4; base + 3 < E; base += stride4) {
    int4 d = *(const int4*)&dst[base];
    atomicAdd(&cnt[d.x], 1);
    atomicAdd(&cnt[d.y], 1);
    atomicAdd(&cnt[d.z], 1);
    atomicAdd(&cnt[d.w], 1);
  }
  int tail0 = (E & ~3);
  int e = tail0 + tid;
  if (e < E) atomicAdd(&cnt[dst[e]], 1);
}

__global__ __launch_bounds__(256) void scanA_k(const int* __restrict__ cnt,
                                               int* __restrict__ bsum, int N) {
  __shared__ int red[256];
  int tid = threadIdx.x;
  int i0 = blockIdx.x * 1024 + tid * 4;
  int s = 0;
  #pragma unroll
  for (int k = 0; k < 4; ++k) { int i = i0 + k; if (i < N) s += cnt[i]; }
  red[tid] = s;
  __syncthreads();
  for (int off = 128; off; off >>= 1) {
    if (tid < off) red[tid] += red[tid + off];
    __syncthreads();
  }
  if (tid == 0) bsum[blockIdx.x] = red[0];
}

__global__ __launch_bounds__(128) void scanB_k(const int* __restrict__ bsum,
                                               int* __restrict__ bbase, int nb) {
  __shared__ int buf[2][128];
  int tid = threadIdx.x;
  buf[0][tid] = (tid < nb) ? bsum[tid] : 0;
  __syncthreads();
  int pin = 0;
  for (int off = 1; off < 128; off <<= 1) {
    int x = buf[pin][tid];
    if (tid >= off) x += buf[pin][tid - off];
    buf[1 - pin][tid] = x;
    __syncthreads();
    pin = 1 - pin;
  }
  if (tid < nb) bbase[tid] = (tid == 0) ? 0 : buf[pin][tid - 1];
}

__global__ __launch_bounds__(256) void scanC_k(const int* __restrict__ cnt,
    const int* __restrict__ bbase, int* __restrict__ rp, int N, int E) {
  __shared__ int buf[2][256];
  int tid = threadIdx.x;
  int i0 = blockIdx.x * 1024 + tid * 4;
  int c[4]; int s = 0;
  #pragma unroll
  for (int k = 0; k < 4; ++k) { int i = i0 + k; c[k] = (i < N) ? cnt[i] : 0; s += c[k]; }
  buf[0][tid] = s;
  __syncthreads();
  int pin = 0;
  for (int off = 1; off < 256; off <<= 1) {
    int x = buf[pin][tid];
    if (tid >= off) x += buf[pin][tid - off];
    buf[1 - pin][tid] = x;
    __syncthreads();
    pin = 1 - pin;
  }
  int run = bbase[blockIdx.x] + buf[pin][tid] - s;
  #pragma unroll
  for (int k = 0; k < 4; ++k) {
    int i = i0 + k;
    if (i < N) { rp[i] = run; run += c[k]; }
  }
  if (blockIdx.x == 0 && tid == 0) rp[N] = E;
}

// scatter into per-node CSR slots; consumes hist counts via atomic decrement
__global__ void scatter_k(const int* __restrict__ src, const int* __restrict__ dst,
                          const float* __restrict__ w, const int* __restrict__ rp,
                          int* __restrict__ cnt, int2* __restrict__ epk, int E) {
  int stride = gridDim.x * blockDim.x;
  for (int e = blockIdx.x * blockDim.x + threadIdx.x; e < E; e += stride) {
    int d = dst[e];
    int off = atomicAdd(&cnt[d], -1) - 1;
    epk[rp[d] + off] = make_int2(src[e], __float_as_int(w[e]));
  }
}

// ---------------- SpMM (pull, CSR by dst, bf16 gather) + initial-residual mix ----------------
__global__ __launch_bounds__(256) void spmm_k(const int* __restrict__ rp,
    const int2* __restrict__ epk, const ushort* __restrict__ hbf,
    const ushort* __restrict__ x0bf, ushort* __restrict__ outbf, int N) {
  int gw = (blockIdx.x * blockDim.x + threadIdx.x) >> 6;
  int lane = threadIdx.x & 63;
  if (gw >= N) return;
  int grp = lane >> 4, l16 = lane & 15;
  int b = __builtin_amdgcn_readfirstlane(rp[gw]);
  int e = __builtin_amdgcn_readfirstlane(rp[gw + 1]);
  float a0 = 0.f, a1 = 0.f, a2 = 0.f, a3 = 0.f;
  float a4 = 0.f, a5 = 0.f, a6 = 0.f, a7 = 0.f;
  const uint* hb = (const uint*)hbf;
  int j = b + grp;
  for (; j + 12 < e; j += 16) {   // this group: edges j, j+4, j+8, j+12
    int2 e0 = epk[j], e1 = epk[j + 4], e2 = epk[j + 8], e3 = epk[j + 12];
    float w0 = __int_as_float(e0.y), w1 = __int_as_float(e1.y);
    float w2 = __int_as_float(e2.y), w3 = __int_as_float(e3.y);
    uint4 h0 = ((const uint4*)hb)[(size_t)e0.x * 16 + l16];
    uint4 h1 = ((const uint4*)hb)[(size_t)e1.x * 16 + l16];
    uint4 h2 = ((const uint4*)hb)[(size_t)e2.x * 16 + l16];
    uint4 h3 = ((const uint4*)hb)[(size_t)e3.x * 16 + l16];
    a0 = fmaf(w0, bflo(h0.x), a0); a1 = fmaf(w0, bfhi(h0.x), a1);
    a2 = fmaf(w0, bflo(h0.y), a2); a3 = fmaf(w0, bfhi(h0.y), a3);
    a4 = fmaf(w0, bflo(h0.z), a4); a5 = fmaf(w0, bfhi(h0.z), a5);
    a6 = fmaf(w0, bflo(h0.w), a6); a7 = fmaf(w0, bfhi(h0.w), a7);
    a0 = fmaf(w1, bflo(h1.x), a0); a1 = fmaf(w1, bfhi(h1.x), a1);
    a2 = fmaf(w1, bflo(h1.y), a2); a3 = fmaf(w1, bfhi(h1.y), a3);
    a4 = fmaf(w1, bflo(h1.z), a4); a5 = fmaf(w1, bfhi(h1.z), a5);
    a6 = fmaf(w1, bflo(h1.w), a6); a7 = fmaf(w1, bfhi(h1.w), a7);
    a0 = fmaf(w2, bflo(h2.x), a0); a1 = fmaf(w2, bfhi(h2.x), a1);
    a2 = fmaf(w2, bflo(h2.y), a2); a3 = fmaf(w2, bfhi(h2.y), a3);
    a4 = fmaf(w2, bflo(h2.z), a4); a5 = fmaf(w2, bfhi(h2.z), a5);
    a6 = fmaf(w2, bflo(h2.w), a6); a7 = fmaf(w2, bfhi(h2.w), a7);
    a0 = fmaf(w3, bflo(h3.x), a0); a1 = fmaf(w3, bfhi(h3.x), a1);
    a2 = fmaf(w3, bflo(h3.y), a2); a3 = fmaf(w3, bfhi(h3.y), a3);
    a4 = fmaf(w3, bflo(h3.z), a4); a5 = fmaf(w3, bfhi(h3.z), a5);
    a6 = fmaf(w3, bflo(h3.w), a6); a7 = fmaf(w3, bfhi(h3.w), a7);
  }
  for (; j + 4 < e; j += 8) {
    int2 e0 = epk[j], e1 = epk[j + 4];
    float w0 = __int_as_float(e0.y), w1 = __int_as_float(e1.y);
    uint4 h0 = ((const uint4*)hb)[(size_t)e0.x * 16 + l16];
    uint4 h1 = ((const uint4*)hb)[(size_t)e1.x * 16 + l16];
    a0 = fmaf(w0, bflo(h0.x), a0); a1 = fmaf(w0, bfhi(h0.x), a1);
    a2 = fmaf(w0, bflo(h0.y), a2); a3 = fmaf(w0, bfhi(h0.y), a3);
    a4 = fmaf(w0, bflo(h0.z), a4); a5 = fmaf(w0, bfhi(h0.z), a5);
    a6 = fmaf(w0, bflo(h0.w), a6); a7 = fmaf(w0, bfhi(h0.w), a7);
    a0 = fmaf(w1, bflo(h1.x), a0); a1 = fmaf(w1, bfhi(h1.x), a1);
    a2 = fmaf(w1, bflo(h1.y), a2); a3 = fmaf(w1, bfhi(h1.y), a3);
    a4 = fmaf(w1, bflo(h1.z), a4); a5 = fmaf(w1, bfhi(h1.z), a5);
    a6 = fmaf(w1, bflo(h1.w), a6); a7 = fmaf(w1, bfhi(h1.w), a7);
  }
  for (; j < e; j += 4) {
    int2 e0 = epk[j];
    float w0 = __int_as_float(e0.y);
    uint4 h0 = ((const uint4*)hb)[(size_t)e0.x * 16 + l16];
    a0 = fmaf(w0, bflo(h0.x), a0); a1 = fmaf(w0, bfhi(h0.x), a1);
    a2 = fmaf(w0, bflo(h0.y), a2); a3 = fmaf(w0, bfhi(h0.y), a3);
    a4 = fmaf(w0, bflo(h0.z), a4); a5 = fmaf(w0, bfhi(h0.z), a5);
    a6 = fmaf(w0, bflo(h0.w), a6); a7 = fmaf(w0, bfhi(h0.w), a7);
  }
  a0 += __shfl_xor(a0, 16); a1 += __shfl_xor(a1, 16);
  a2 += __shfl_xor(a2, 16); a3 += __shfl_xor(a3, 16);
  a4 += __shfl_xor(a4, 16); a5 += __shfl_xor(a5, 16);
  a6 += __shfl_xor(a6, 16); a7 += __shfl_xor(a7, 16);
  a0 += __shfl_xor(a0, 32); a1 += __shfl_xor(a1, 32);
  a2 += __shfl_xor(a2, 32); a3 += __shfl_xor(a3, 32);
  a4 += __shfl_xor(a4, 32); a5 += __shfl_xor(a5, 32);
  a6 += __shfl_xor(a6, 32); a7 += __shfl_xor(a7, 32);
  if (grp == 0) {
    uint4 xv = ((const uint4*)x0bf)[(size_t)gw * 16 + l16];
    float o0 = 0.9f * a0 + 0.1f * bflo(xv.x);
    float o1 = 0.9f * a1 + 0.1f * bfhi(xv.x);
    float o2 = 0.9f * a2 + 0.1f * bflo(xv.y);
    float o3 = 0.9f * a3 + 0.1f * bfhi(xv.y);
    float o4 = 0.9f * a4 + 0.1f * bflo(xv.z);
    float o5 = 0.9f * a5 + 0.1f * bfhi(xv.z);
    float o6 = 0.9f * a6 + 0.1f * bflo(xv.w);
    float o7 = 0.9f * a7 + 0.1f * bfhi(xv.w);
    uint4 u;
    u.x = packbf2(o0, o1); u.y = packbf2(o2, o3);
    u.z = packbf2(o4, o5); u.w = packbf2(o6, o7);
    ((uint4*)outbf)[(size_t)gw * 16 + l16] = u;
  }
}

// ---------------- MFMA dense GEMM: 128 rows/block, full K=128, N=128 ----------------
// 4 waves x 32 rows; per wave 2 row-tiles x 8 col-tiles of 16x16, K-steps of 32.
// A fragments direct from global (row = lane&15, k = 8*(lane>>4)+j, 16B/lane).
// W transpose-staged to LDS bf16 Wt[n][k] (+8 pad); B-frag = 16B ds_read.
// D layout (m89-verified): col = lane&15, row = 4*(lane>>4) + reg.
// MODE 0 (proj, ABF=0): y = relu(in@W + bias); bf16 -> outbf (h) and outbf2 (x0)
// MODE 1 (conv, ABF=1): y = relu(cin*in + cw*(in@W)); bf16 -> outbf
// MODE 2 (final,ABF=1): y = log_softmax(in@W + bias); f32 -> outf
template<int MODE, int ABF>
__global__ __launch_bounds__(256, 4) void gemm_mfma(const void* __restrict__ inv,
    const float* __restrict__ W, const float* __restrict__ bias,
    float* __restrict__ outf, ushort* __restrict__ outbf, ushort* __restrict__ outbf2,
    float cin, float cw, int N) {
  __shared__ ushort Wt[128][136];
  const float*  inf = (const float*)inv;
  const ushort* inb = (const ushort*)inv;
  int tid = threadIdx.x;

  // stage W transposed, f32 -> bf16
  for (int i = tid; i < 128 * 32; i += 256) {
    int k = i >> 5, n4 = (i & 31) << 2;
    float4 v = *(const float4*)&W[(size_t)k * 128 + n4];
    Wt[n4 + 0][k] = f2bf(v.x);
    Wt[n4 + 1][k] = f2bf(v.y);
    Wt[n4 + 2][k] = f2bf(v.z);
    Wt[n4 + 3][k] = f2bf(v.w);
  }
  __syncthreads();

  int w = tid >> 6, lane = tid & 63;
  int l15 = lane & 15, hi = lane >> 4;
  int rbase = blockIdx.x * 128 + w * 32;

  f32x4 acc[2][8];
  #pragma unroll
  for (int mi = 0; mi < 2; ++mi)
    #pragma unroll
    for (int ni = 0; ni < 8; ++ni)
      acc[mi][ni] = (f32x4){0.f, 0.f, 0.f, 0.f};

  int r0 = min(rbase + l15, N - 1);
  int r1 = min(rbase + 16 + l15, N - 1);

  #pragma unroll
  for (int kt = 0; kt < 4; ++kt) {
    int koff = kt * 32 + hi * 8;
    bf8 a0, a1;
    if (ABF) {
      a0 = *(const bf8*)&inb[(size_t)r0 * 128 + koff];
      a1 = *(const bf8*)&inb[(size_t)r1 * 128 + koff];
    } else {
      float4 f0 = *(const float4*)&inf[(size_t)r0 * 128 + koff];
      float4 f1 = *(const float4*)&inf[(size_t)r0 * 128 + koff + 4];
      float4 g0 = *(const float4*)&inf[(size_t)r1 * 128 + koff];
      float4 g1 = *(const float4*)&inf[(size_t)r1 * 128 + koff + 4];
      union { bf8 v; uint u[4]; } ta, tb;
      ta.u[0] = packbf2(f0.x, f0.y); ta.u[1] = packbf2(f0.z, f0.w);
      ta.u[2] = packbf2(f1.x, f1.y); ta.u[3] = packbf2(f1.z, f1.w);
      tb.u[0] = packbf2(g0.x, g0.y); tb.u[1] = packbf2(g0.z, g0.w);
      tb.u[2] = packbf2(g1.x, g1.y); tb.u[3] = packbf2(g1.z, g1.w);
      a0 = ta.v; a1 = tb.v;
    }
    #pragma unroll
    for (int ni = 0; ni < 8; ++ni) {
      bf8 b = *(const bf8*)&Wt[ni * 16 + l15][koff];
      acc[0][ni] = __builtin_amdgcn_mfma_f32_16x16x32_bf16(a0, b, acc[0][ni], 0, 0, 0);
      acc[1][ni] = __builtin_amdgcn_mfma_f32_16x16x32_bf16(a1, b, acc[1][ni], 0, 0, 0);
    }
  }

  float bcol[8];
  if (MODE != 1) {
    #pragma unroll
    for (int ni = 0; ni < 8; ++ni) bcol[ni] = bias[ni * 16 + l15];
  }

  #pragma unroll
  for (int mi = 0; mi < 2; ++mi) {
    #pragma unroll
    for (int reg = 0; reg < 4; ++reg) {
      int row = rbase + mi * 16 + 4 * hi + reg;
      bool valid = (row < N);
      float y[8];
      #pragma unroll
      for (int ni = 0; ni < 8; ++ni) y[ni] = acc[mi][ni][reg];
      if (MODE == 1) {
        if (valid) {
          #pragma unroll
          for (int ni = 0; ni < 8; ++ni) {
            float iv = bf2f(inb[(size_t)row * 128 + ni * 16 + l15]);
            y[ni] = fmaxf(cin * iv + cw * y[ni], 0.f);
          }
        }
      } else {
        #pragma unroll
        for (int ni = 0; ni < 8; ++ni) y[ni] += bcol[ni];
        if (MODE == 0) {
          #pragma unroll
          for (int ni = 0; ni < 8; ++ni) y[ni] = fmaxf(y[ni], 0.f);
        }
      }
      if (MODE == 2) {
        // row is uniform across the 16-lane group; cols spread over lanes+ni
        float m = y[0];
        #pragma unroll
        for (int ni = 1; ni < 8; ++ni) m = fmaxf(m, y[ni]);
        #pragma unroll
        for (int off = 1; off <= 8; off <<= 1) m = fmaxf(m, __shfl_xor(m, off));
        float s = 0.f;
        #pragma unroll
        for (int ni = 0; ni < 8; ++ni) s += expf(y[ni] - m);
        #pragma unroll
        for (int off = 1; off <= 8; off <<= 1) s += __shfl_xor(s, off);
        float lg = m + logf(s);
        #pragma unroll
        for (int ni = 0; ni < 8; ++ni) y[ni] -= lg;
      }
      if (valid) {
        if (MODE == 2) {
          #pragma unroll
          for (int ni = 0; ni < 8; ++ni)
            outf[(size_t)row * 128 + ni * 16 + l15] = y[ni];
        } else {
          #pragma unroll
          for (int ni = 0; ni < 8; ++ni) {
            ushort u = f2bf(y[ni]);
            outbf[(size_t)row * 128 + ni * 16 + l15] = u;
            if (MODE == 0) outbf2[(size_t)row * 128 + ni * 16 + l15] = u;
          }
        }
      }
    }
  }
}

extern "C" void kernel_launch(void* const* d_in, const int* in_sizes, int n_in,
                              void* d_out, int out_size, void* d_ws, size_t ws_size,
                              hipStream_t stream) {
  const float* x     = (const float*)d_in[0];
  const int*   esrc  = (const int*)d_in[1];
  const int*   edst  = (const int*)d_in[2];
  const float* ew    = (const float*)d_in[3];
  const float* W0    = (const float*)d_in[4];
  const float* b0    = (const float*)d_in[5];
  const float* W1    = (const float*)d_in[6];
  const float* b1    = (const float*)d_in[7];
  const float* convW = (const float*)d_in[8];
  int N = in_sizes[0] / 128;
  int E = in_sizes[1];
  float* outp = (float*)d_out;

  char* ws = (char*)d_ws;
  size_t off = 0;
  auto alloc = [&](size_t bytes) {
    void* p = ws + off;
    off += (bytes + 255) & ~(size_t)255;
    return p;
  };
  ushort* hbf   = (ushort*)alloc((size_t)N * 128 * 2);
  ushort* x0bf  = (ushort*)alloc((size_t)N * 128 * 2);
  ushort* bufB  = (ushort*)alloc((size_t)N * 128 * 2);   // spmm out (bf16)
  ushort* bufA  = (ushort*)alloc((size_t)N * 128 * 2);   // final-GEMM input (bf16)
  int*    rp    = (int*)alloc((size_t)(N + 1) * 4);
  int*    cnt   = (int*)alloc((size_t)N * 4);
  int2*   epk   = (int2*)alloc((size_t)E * 8);
  int nbScan = (N + 1023) / 1024;
  int*    bsum  = (int*)alloc((size_t)nbScan * 4);
  int*    bbase = (int*)alloc((size_t)nbScan * 4);

  // ---- CSR build ----
  hipMemsetAsync(cnt, 0, (size_t)N * 4, stream);
  hist_k<<<2048, 256, 0, stream>>>(edst, cnt, E);
  scanA_k<<<nbScan, 256, 0, stream>>>(cnt, bsum, N);
  scanB_k<<<1, 128, 0, stream>>>(bsum, bbase, nbScan);
  scanC_k<<<nbScan, 256, 0, stream>>>(cnt, bbase, rp, N, E);
  scatter_k<<<2048, 256, 0, stream>>>(esrc, edst, ew, rp, cnt, epk, E);

  int gemmBlocks = (N + 127) / 128;
  int spmmBlocks = (N + 3) / 4;

  // ---- input projection: h = relu(x@W0 + b0) -> hbf, x0bf (bf16) ----
  gemm_mfma<0, 0><<<gemmBlocks, 256, 0, stream>>>(x, W0, b0, nullptr, hbf, x0bf, 0.f, 1.f, N);

  // ---- 4 GCNII layers ----
  for (int l = 0; l < 4; ++l) {
    float beta = logf(0.5f / (float)(l + 1) + 1.f);
    spmm_k<<<spmmBlocks, 256, 0, stream>>>(rp, epk, hbf, x0bf, bufB, N);
    gemm_mfma<1, 1><<<gemmBlocks, 256, 0, stream>>>(
        bufB, convW + (size_t)l * 128 * 128, nullptr,
        nullptr, (l == 3) ? bufA : hbf, nullptr,
        1.f - beta, beta, N);
  }

  // ---- final: logits + log_softmax ----
  gemm_mfma<2, 1><<<gemmBlocks, 256, 0, stream>>>(bufA, W1, b1, outp, nullptr, nullptr, 0.f, 1.f, N);
}

// Round 9
// 582.583 us; speedup vs baseline: 1.5896x; 1.0230x over previous
//
#include <hip/hip_runtime.h>
#include <math.h>

typedef unsigned int uint;
typedef unsigned short ushort;
using bf8   = __attribute__((ext_vector_type(8))) short;   // 8 bf16 (4 VGPRs)
using f32x4 = __attribute__((ext_vector_type(4))) float;   // 4 fp32

__device__ inline ushort f2bf(float f) {
  uint u = __float_as_uint(f);
  return (ushort)((u + 0x7fffu + ((u >> 16) & 1u)) >> 16);
}
__device__ inline float bf2f(ushort s) { return __uint_as_float(((uint)s) << 16); }
__device__ inline uint packbf2(float a, float b) {
  uint ua = __float_as_uint(a), ub = __float_as_uint(b);
  ua = (ua + 0x7fffu + ((ua >> 16) & 1u)) >> 16;
  ub = (ub + 0x7fffu + ((ub >> 16) & 1u)) & 0xffff0000u;
  return ua | ub;
}
__device__ inline float bflo(uint u) { return __uint_as_float(u << 16); }
__device__ inline float bfhi(uint u) { return __uint_as_float(u & 0xffff0000u); }

// ---------------- CSR build ----------------
__global__ void hist_k(const int* __restrict__ dst, int* __restrict__ cnt, int E) {
  int tid = blockIdx.x * blockDim.x + threadIdx.x;
  int stride4 = gridDim.x * blockDim.x * 4;
  for (int base = tid * 4; base + 3 < E; base += stride4) {
    int4 d = *(const int4*)&dst[base];
    atomicAdd(&cnt[d.x], 1);
    atomicAdd(&cnt[d.y], 1);
    atomicAdd(&cnt[d.z], 1);
    atomicAdd(&cnt[d.w], 1);
  }
  int tail0 = (E & ~3);
  int e = tail0 + tid;
  if (e < E) atomicAdd(&cnt[dst[e]], 1);
}

__global__ __launch_bounds__(256) void scanA_k(const int* __restrict__ cnt,
                                               int* __restrict__ bsum, int N) {
  __shared__ int red[256];
  int tid = threadIdx.x;
  int i0 = blockIdx.x * 1024 + tid * 4;
  int s = 0;
  #pragma unroll
  for (int k = 0; k < 4; ++k) { int i = i0 + k; if (i < N) s += cnt[i]; }
  red[tid] = s;
  __syncthreads();
  for (int off = 128; off; off >>= 1) {
    if (tid < off) red[tid] += red[tid + off];
    __syncthreads();
  }
  if (tid == 0) bsum[blockIdx.x] = red[0];
}

__global__ __launch_bounds__(128) void scanB_k(const int* __restrict__ bsum,
                                               int* __restrict__ bbase, int nb) {
  __shared__ int buf[2][128];
  int tid = threadIdx.x;
  buf[0][tid] = (tid < nb) ? bsum[tid] : 0;
  __syncthreads();
  int pin = 0;
  for (int off = 1; off < 128; off <<= 1) {
    int x = buf[pin][tid];
    if (tid >= off) x += buf[pin][tid - off];
    buf[1 - pin][tid] = x;
    __syncthreads();
    pin = 1 - pin;
  }
  if (tid < nb) bbase[tid] = (tid == 0) ? 0 : buf[pin][tid - 1];
}

__global__ __launch_bounds__(256) void scanC_k(const int* __restrict__ cnt,
    const int* __restrict__ bbase, int* __restrict__ rp, int N, int E) {
  __shared__ int buf[2][256];
  int tid = threadIdx.x;
  int i0 = blockIdx.x * 1024 + tid * 4;
  int c[4]; int s = 0;
  #pragma unroll
  for (int k = 0; k < 4; ++k) { int i = i0 + k; c[k] = (i < N) ? cnt[i] : 0; s += c[k]; }
  buf[0][tid] = s;
  __syncthreads();
  int pin = 0;
  for (int off = 1; off < 256; off <<= 1) {
    int x = buf[pin][tid];
    if (tid >= off) x += buf[pin][tid - off];
    buf[1 - pin][tid] = x;
    __syncthreads();
    pin = 1 - pin;
  }
  int run = bbase[blockIdx.x] + buf[pin][tid] - s;
  #pragma unroll
  for (int k = 0; k < 4; ++k) {
    int i = i0 + k;
    if (i < N) { rp[i] = run; run += c[k]; }
  }
  if (blockIdx.x == 0 && tid == 0) rp[N] = E;
}

// scatter into per-node CSR slots; consumes hist counts via atomic decrement
__global__ void scatter_k(const int* __restrict__ src, const int* __restrict__ dst,
                          const float* __restrict__ w, const int* __restrict__ rp,
                          int* __restrict__ cnt, int2* __restrict__ epk, int E) {
  int stride = gridDim.x * blockDim.x;
  for (int e = blockIdx.x * blockDim.x + threadIdx.x; e < E; e += stride) {
    int d = dst[e];
    int off = atomicAdd(&cnt[d], -1) - 1;
    epk[rp[d] + off] = make_int2(src[e], __float_as_int(w[e]));
  }
}

// ---------------- SpMM (pull, CSR by dst, bf16 gather) + initial-residual mix ----------------
// ONE NODE PER 16-LANE GROUP (degree ~Poisson(16): a group walking its own
// node's full edge list hits the 4-deep unrolled path at degree>=4, vs the old
// 4-group-split which needed degree>=52). 4 gathers in flight per group,
// 16 groups/block. No cross-lane combine needed.
__global__ __launch_bounds__(256) void spmm_k(const int* __restrict__ rp,
    const int2* __restrict__ epk, const ushort* __restrict__ hbf,
    const ushort* __restrict__ x0bf, ushort* __restrict__ outbf, int N) {
  int node = (blockIdx.x * blockDim.x + threadIdx.x) >> 4;
  int l16 = threadIdx.x & 15;
  if (node >= N) return;
  int b = rp[node], e = rp[node + 1];
  float a0 = 0.f, a1 = 0.f, a2 = 0.f, a3 = 0.f;
  float a4 = 0.f, a5 = 0.f, a6 = 0.f, a7 = 0.f;
  const uint4* hb4 = (const uint4*)hbf;
  int j = b;
  for (; j + 3 < e; j += 4) {
    int2 e0 = epk[j], e1 = epk[j + 1], e2 = epk[j + 2], e3 = epk[j + 3];
    float w0 = __int_as_float(e0.y), w1 = __int_as_float(e1.y);
    float w2 = __int_as_float(e2.y), w3 = __int_as_float(e3.y);
    uint4 h0 = hb4[(size_t)e0.x * 16 + l16];
    uint4 h1 = hb4[(size_t)e1.x * 16 + l16];
    uint4 h2 = hb4[(size_t)e2.x * 16 + l16];
    uint4 h3 = hb4[(size_t)e3.x * 16 + l16];
    a0 = fmaf(w0, bflo(h0.x), a0); a1 = fmaf(w0, bfhi(h0.x), a1);
    a2 = fmaf(w0, bflo(h0.y), a2); a3 = fmaf(w0, bfhi(h0.y), a3);
    a4 = fmaf(w0, bflo(h0.z), a4); a5 = fmaf(w0, bfhi(h0.z), a5);
    a6 = fmaf(w0, bflo(h0.w), a6); a7 = fmaf(w0, bfhi(h0.w), a7);
    a0 = fmaf(w1, bflo(h1.x), a0); a1 = fmaf(w1, bfhi(h1.x), a1);
    a2 = fmaf(w1, bflo(h1.y), a2); a3 = fmaf(w1, bfhi(h1.y), a3);
    a4 = fmaf(w1, bflo(h1.z), a4); a5 = fmaf(w1, bfhi(h1.z), a5);
    a6 = fmaf(w1, bflo(h1.w), a6); a7 = fmaf(w1, bfhi(h1.w), a7);
    a0 = fmaf(w2, bflo(h2.x), a0); a1 = fmaf(w2, bfhi(h2.x), a1);
    a2 = fmaf(w2, bflo(h2.y), a2); a3 = fmaf(w2, bfhi(h2.y), a3);
    a4 = fmaf(w2, bflo(h2.z), a4); a5 = fmaf(w2, bfhi(h2.z), a5);
    a6 = fmaf(w2, bflo(h2.w), a6); a7 = fmaf(w2, bfhi(h2.w), a7);
    a0 = fmaf(w3, bflo(h3.x), a0); a1 = fmaf(w3, bfhi(h3.x), a1);
    a2 = fmaf(w3, bflo(h3.y), a2); a3 = fmaf(w3, bfhi(h3.y), a3);
    a4 = fmaf(w3, bflo(h3.z), a4); a5 = fmaf(w3, bfhi(h3.z), a5);
    a6 = fmaf(w3, bflo(h3.w), a6); a7 = fmaf(w3, bfhi(h3.w), a7);
  }
  for (; j < e; ++j) {
    int2 e0 = epk[j];
    float w0 = __int_as_float(e0.y);
    uint4 h0 = hb4[(size_t)e0.x * 16 + l16];
    a0 = fmaf(w0, bflo(h0.x), a0); a1 = fmaf(w0, bfhi(h0.x), a1);
    a2 = fmaf(w0, bflo(h0.y), a2); a3 = fmaf(w0, bfhi(h0.y), a3);
    a4 = fmaf(w0, bflo(h0.z), a4); a5 = fmaf(w0, bfhi(h0.z), a5);
    a6 = fmaf(w0, bflo(h0.w), a6); a7 = fmaf(w0, bfhi(h0.w), a7);
  }
  uint4 xv = ((const uint4*)x0bf)[(size_t)node * 16 + l16];
  float o0 = 0.9f * a0 + 0.1f * bflo(xv.x);
  float o1 = 0.9f * a1 + 0.1f * bfhi(xv.x);
  float o2 = 0.9f * a2 + 0.1f * bflo(xv.y);
  float o3 = 0.9f * a3 + 0.1f * bfhi(xv.y);
  float o4 = 0.9f * a4 + 0.1f * bflo(xv.z);
  float o5 = 0.9f * a5 + 0.1f * bfhi(xv.z);
  float o6 = 0.9f * a6 + 0.1f * bflo(xv.w);
  float o7 = 0.9f * a7 + 0.1f * bfhi(xv.w);
  uint4 u;
  u.x = packbf2(o0, o1); u.y = packbf2(o2, o3);
  u.z = packbf2(o4, o5); u.w = packbf2(o6, o7);
  ((uint4*)outbf)[(size_t)node * 16 + l16] = u;
}

// ---------------- MFMA dense GEMM: 128 rows/block, full K=128, N=128 ----------------
// 4 waves x 32 rows; per wave 2 row-tiles x 8 col-tiles of 16x16, K-steps of 32.
// A fragments direct from global (row = lane&15, k = 8*(lane>>4)+j, 16B/lane).
// W transpose-staged to LDS bf16 Wt[n][k] (+8 pad); B-frag = 16B ds_read.
// D layout (m89-verified): col = lane&15, row = 4*(lane>>4) + reg.
// MODE 0 (proj, ABF=0): y = relu(in@W + bias); bf16 -> outbf (h) and outbf2 (x0)
// MODE 1 (conv, ABF=1): y = relu(cin*in + cw*(in@W)); bf16 -> outbf
// MODE 2 (final,ABF=1): y = log_softmax(in@W + bias); f32 -> outf
template<int MODE, int ABF>
__global__ __launch_bounds__(256, 4) void gemm_mfma(const void* __restrict__ inv,
    const float* __restrict__ W, const float* __restrict__ bias,
    float* __restrict__ outf, ushort* __restrict__ outbf, ushort* __restrict__ outbf2,
    float cin, float cw, int N) {
  __shared__ ushort Wt[128][136];
  const float*  inf = (const float*)inv;
  const ushort* inb = (const ushort*)inv;
  int tid = threadIdx.x;

  // stage W transposed, f32 -> bf16
  for (int i = tid; i < 128 * 32; i += 256) {
    int k = i >> 5, n4 = (i & 31) << 2;
    float4 v = *(const float4*)&W[(size_t)k * 128 + n4];
    Wt[n4 + 0][k] = f2bf(v.x);
    Wt[n4 + 1][k] = f2bf(v.y);
    Wt[n4 + 2][k] = f2bf(v.z);
    Wt[n4 + 3][k] = f2bf(v.w);
  }
  __syncthreads();

  int w = tid >> 6, lane = tid & 63;
  int l15 = lane & 15, hi = lane >> 4;
  int rbase = blockIdx.x * 128 + w * 32;

  f32x4 acc[2][8];
  #pragma unroll
  for (int mi = 0; mi < 2; ++mi)
    #pragma unroll
    for (int ni = 0; ni < 8; ++ni)
      acc[mi][ni] = (f32x4){0.f, 0.f, 0.f, 0.f};

  int r0 = min(rbase + l15, N - 1);
  int r1 = min(rbase + 16 + l15, N - 1);

  #pragma unroll
  for (int kt = 0; kt < 4; ++kt) {
    int koff = kt * 32 + hi * 8;
    bf8 a0, a1;
    if (ABF) {
      a0 = *(const bf8*)&inb[(size_t)r0 * 128 + koff];
      a1 = *(const bf8*)&inb[(size_t)r1 * 128 + koff];
    } else {
      float4 f0 = *(const float4*)&inf[(size_t)r0 * 128 + koff];
      float4 f1 = *(const float4*)&inf[(size_t)r0 * 128 + koff + 4];
      float4 g0 = *(const float4*)&inf[(size_t)r1 * 128 + koff];
      float4 g1 = *(const float4*)&inf[(size_t)r1 * 128 + koff + 4];
      union { bf8 v; uint u[4]; } ta, tb;
      ta.u[0] = packbf2(f0.x, f0.y); ta.u[1] = packbf2(f0.z, f0.w);
      ta.u[2] = packbf2(f1.x, f1.y); ta.u[3] = packbf2(f1.z, f1.w);
      tb.u[0] = packbf2(g0.x, g0.y); tb.u[1] = packbf2(g0.z, g0.w);
      tb.u[2] = packbf2(g1.x, g1.y); tb.u[3] = packbf2(g1.z, g1.w);
      a0 = ta.v; a1 = tb.v;
    }
    #pragma unroll
    for (int ni = 0; ni < 8; ++ni) {
      bf8 b = *(const bf8*)&Wt[ni * 16 + l15][koff];
      acc[0][ni] = __builtin_amdgcn_mfma_f32_16x16x32_bf16(a0, b, acc[0][ni], 0, 0, 0);
      acc[1][ni] = __builtin_amdgcn_mfma_f32_16x16x32_bf16(a1, b, acc[1][ni], 0, 0, 0);
    }
  }

  float bcol[8];
  if (MODE != 1) {
    #pragma unroll
    for (int ni = 0; ni < 8; ++ni) bcol[ni] = bias[ni * 16 + l15];
  }

  #pragma unroll
  for (int mi = 0; mi < 2; ++mi) {
    #pragma unroll
    for (int reg = 0; reg < 4; ++reg) {
      int row = rbase + mi * 16 + 4 * hi + reg;
      bool valid = (row < N);
      float y[8];
      #pragma unroll
      for (int ni = 0; ni < 8; ++ni) y[ni] = acc[mi][ni][reg];
      if (MODE == 1) {
        if (valid) {
          #pragma unroll
          for (int ni = 0; ni < 8; ++ni) {
            float iv = bf2f(inb[(size_t)row * 128 + ni * 16 + l15]);
            y[ni] = fmaxf(cin * iv + cw * y[ni], 0.f);
          }
        }
      } else {
        #pragma unroll
        for (int ni = 0; ni < 8; ++ni) y[ni] += bcol[ni];
        if (MODE == 0) {
          #pragma unroll
          for (int ni = 0; ni < 8; ++ni) y[ni] = fmaxf(y[ni], 0.f);
        }
      }
      if (MODE == 2) {
        float m = y[0];
        #pragma unroll
        for (int ni = 1; ni < 8; ++ni) m = fmaxf(m, y[ni]);
        #pragma unroll
        for (int off = 1; off <= 8; off <<= 1) m = fmaxf(m, __shfl_xor(m, off));
        float s = 0.f;
        #pragma unroll
        for (int ni = 0; ni < 8; ++ni) s += expf(y[ni] - m);
        #pragma unroll
        for (int off = 1; off <= 8; off <<= 1) s += __shfl_xor(s, off);
        float lg = m + logf(s);
        #pragma unroll
        for (int ni = 0; ni < 8; ++ni) y[ni] -= lg;
      }
      if (valid) {
        if (MODE == 2) {
          #pragma unroll
          for (int ni = 0; ni < 8; ++ni)
            outf[(size_t)row * 128 + ni * 16 + l15] = y[ni];
        } else {
          #pragma unroll
          for (int ni = 0; ni < 8; ++ni) {
            ushort u = f2bf(y[ni]);
            outbf[(size_t)row * 128 + ni * 16 + l15] = u;
            if (MODE == 0) outbf2[(size_t)row * 128 + ni * 16 + l15] = u;
          }
        }
      }
    }
  }
}

extern "C" void kernel_launch(void* const* d_in, const int* in_sizes, int n_in,
                              void* d_out, int out_size, void* d_ws, size_t ws_size,
                              hipStream_t stream) {
  const float* x     = (const float*)d_in[0];
  const int*   esrc  = (const int*)d_in[1];
  const int*   edst  = (const int*)d_in[2];
  const float* ew    = (const float*)d_in[3];
  const float* W0    = (const float*)d_in[4];
  const float* b0    = (const float*)d_in[5];
  const float* W1    = (const float*)d_in[6];
  const float* b1    = (const float*)d_in[7];
  const float* convW = (const float*)d_in[8];
  int N = in_sizes[0] / 128;
  int E = in_sizes[1];
  float* outp = (float*)d_out;

  char* ws = (char*)d_ws;
  size_t off = 0;
  auto alloc = [&](size_t bytes) {
    void* p = ws + off;
    off += (bytes + 255) & ~(size_t)255;
    return p;
  };
  ushort* hbf   = (ushort*)alloc((size_t)N * 128 * 2);
  ushort* x0bf  = (ushort*)alloc((size_t)N * 128 * 2);
  ushort* bufB  = (ushort*)alloc((size_t)N * 128 * 2);   // spmm out (bf16)
  ushort* bufA  = (ushort*)alloc((size_t)N * 128 * 2);   // final-GEMM input (bf16)
  int*    rp    = (int*)alloc((size_t)(N + 1) * 4);
  int*    cnt   = (int*)alloc((size_t)N * 4);
  int2*   epk   = (int2*)alloc((size_t)E * 8);
  int nbScan = (N + 1023) / 1024;
  int*    bsum  = (int*)alloc((size_t)nbScan * 4);
  int*    bbase = (int*)alloc((size_t)nbScan * 4);

  // ---- CSR build ----
  hipMemsetAsync(cnt, 0, (size_t)N * 4, stream);
  hist_k<<<2048, 256, 0, stream>>>(edst, cnt, E);
  scanA_k<<<nbScan, 256, 0, stream>>>(cnt, bsum, N);
  scanB_k<<<1, 128, 0, stream>>>(bsum, bbase, nbScan);
  scanC_k<<<nbScan, 256, 0, stream>>>(cnt, bbase, rp, N, E);
  scatter_k<<<2048, 256, 0, stream>>>(esrc, edst, ew, rp, cnt, epk, E);

  int gemmBlocks = (N + 127) / 128;
  int spmmBlocks = (N + 15) / 16;   // one node per 16-lane group

  // ---- input projection: h = relu(x@W0 + b0) -> hbf, x0bf (bf16) ----
  gemm_mfma<0, 0><<<gemmBlocks, 256, 0, stream>>>(x, W0, b0, nullptr, hbf, x0bf, 0.f, 1.f, N);

  // ---- 4 GCNII layers ----
  for (int l = 0; l < 4; ++l) {
    float beta = logf(0.5f / (float)(l + 1) + 1.f);
    spmm_k<<<spmmBlocks, 256, 0, stream>>>(rp, epk, hbf, x0bf, bufB, N);
    gemm_mfma<1, 1><<<gemmBlocks, 256, 0, stream>>>(
        bufB, convW + (size_t)l * 128 * 128, nullptr,
        nullptr, (l == 3) ? bufA : hbf, nullptr,
        1.f - beta, beta, N);
  }

  // ---- final: logits + log_softmax ----
  gemm_mfma<2, 1><<<gemmBlocks, 256, 0, stream>>>(bufA, W1, b1, outp, nullptr, nullptr, 0.f, 1.f, N);
}